// Round 2
// baseline (1827.141 us; speedup 1.0000x reference)
//
#include <hip/hip_runtime.h>

#define TTOT 16384        // 4 * 4096 tokens
#define DDIM 2048
#define NEXP 64
#define TPB  16           // tokens per block
#define SLICE 128         // d staged per slice
#define NSLICE (DDIM / SLICE)
#define XP 20             // LDS x-row: 16 tok + 4 pad (floats)
#define LPAD 65           // combine-buffer row (doubles)

// R2 restructure: block = 256 thr (4 waves) owns 16 tokens x 64 experts.
// Wave wq computes a 32-d chunk of each 128-d LDS slice. Per lane: T=4 x E=4
// -> acc64[4][4] (32 regs, was 64) frees budget for __launch_bounds__(256,5)
// (20 waves/CU vs 16) AND an explicit depth-4 rolling W prefetch (wr[4]) so
// each wave's W load-to-use distance ~4 dd-iterations. fp32 chains kept at
// length 16 (fp64 convert at dd=16 midpoint) + fp64 cross-chunk + fp64 LDS
// combine = identical numerics structure to the proven R1 kernel. L overlaid
// on xs (L live only post-loop): LDS 20.5 KB, never the occupancy binder.
__global__ __launch_bounds__(256, 5)
void moe_router(const float* __restrict__ x, const float* __restrict__ W,
                float* __restrict__ out)
{
    __shared__ __align__(16) unsigned char smem[
        (2 * SLICE * XP * 4 > TPB * LPAD * 8) ? (2 * SLICE * XP * 4)
                                              : (TPB * LPAD * 8)];
    typedef float  XS_t[2][SLICE][XP];
    typedef double L_t[TPB][LPAD];
    XS_t& xs = *reinterpret_cast<XS_t*>(smem);
    L_t&  L  = *reinterpret_cast<L_t*>(smem);

    const int tid  = threadIdx.x;
    const int lane = tid & 63;
    const int wq   = __builtin_amdgcn_readfirstlane(tid >> 6);  // 0..3
    const int eg   = lane & 15;       // experts [4eg, 4eg+4)
    const int tg   = lane >> 4;       // tokens  [4tg, 4tg+4)
    const int tokBase = blockIdx.x * TPB;

    // stager map: thread stages token st at d-offsets sd0..sd0+3 (+64)
    const int st  = tid & 15;
    const int sd0 = (tid >> 4) << 2;        // 0..60
    const float* sx = x + (size_t)(tokBase + st) * DDIM;

    double acc64[4][4];
#pragma unroll
    for (int t = 0; t < 4; ++t)
#pragma unroll
        for (int j = 0; j < 4; ++j) acc64[t][j] = 0.0;

    // stage slice 0
    {
        float4 g0 = *(const float4*)(sx + sd0);
        float4 g1 = *(const float4*)(sx + 64 + sd0);
        const float v0[4] = {g0.x, g0.y, g0.z, g0.w};
        const float v1[4] = {g1.x, g1.y, g1.z, g1.w};
#pragma unroll
        for (int j = 0; j < 4; ++j) {
            xs[0][sd0 + j][st]      = v0[j];
            xs[0][64 + sd0 + j][st] = v1[j];
        }
    }
    __syncthreads();

    int buf = 0;
    for (int s = 0; s < NSLICE; ++s) {
        const int dbase = wq * 32;
        const float* Wp = W + (size_t)(s * SLICE + dbase) * NEXP + 4 * eg;

        // W pipeline: preload rows 0..3 FIRST (oldest in vmcnt order, so
        // their waits never block on the slower x staging loads below)
        float4 wr[4];
#pragma unroll
        for (int k = 0; k < 4; ++k)
            wr[k] = *(const float4*)(Wp + (size_t)k * NEXP);

        // issue next slice's x loads (consumed only at slice end)
        float4 g0, g1;
        if (s + 1 < NSLICE) {
            const float* nx = sx + (s + 1) * SLICE;
            g0 = *(const float4*)(nx + sd0);
            g1 = *(const float4*)(nx + 64 + sd0);
        }

        float a32[4][4];
#pragma unroll
        for (int t = 0; t < 4; ++t)
#pragma unroll
            for (int j = 0; j < 4; ++j) a32[t][j] = 0.0f;

#pragma unroll
        for (int h = 0; h < 2; ++h) {
#pragma unroll
            for (int dd4 = 0; dd4 < 16; dd4 += 4) {
#pragma unroll
                for (int k = 0; k < 4; ++k) {
                    const int dd = h * 16 + dd4 + k;
                    const float4 wv = wr[k];
                    if (dd + 4 < 32)   // constant after full unroll
                        wr[k] = *(const float4*)(Wp + (size_t)(dd + 4) * NEXP);
                    const float4 xv = *(const float4*)&xs[buf][dbase + dd][4 * tg];
                    const float xt[4] = {xv.x, xv.y, xv.z, xv.w};
                    const float wj[4] = {wv.x, wv.y, wv.z, wv.w};
#pragma unroll
                    for (int t = 0; t < 4; ++t)
#pragma unroll
                        for (int j = 0; j < 4; ++j)
                            a32[t][j] = fmaf(xt[t], wj[j], a32[t][j]);
                }
            }
            // keep fp32 chain length at 16: convert at each 16-d boundary
#pragma unroll
            for (int t = 0; t < 4; ++t)
#pragma unroll
                for (int j = 0; j < 4; ++j) {
                    acc64[t][j] += (double)a32[t][j];
                    a32[t][j] = 0.0f;
                }
        }

        // write next slice into the other buffer, one barrier per slice
        if (s + 1 < NSLICE) {
            const int nb = buf ^ 1;
            const float v0[4] = {g0.x, g0.y, g0.z, g0.w};
            const float v1[4] = {g1.x, g1.y, g1.z, g1.w};
#pragma unroll
            for (int j = 0; j < 4; ++j) {
                xs[nb][sd0 + j][st]      = v0[j];
                xs[nb][64 + sd0 + j][st] = v1[j];
            }
            __syncthreads();
            buf = nb;
        }
    }
    __syncthreads();   // all xs reads done before L overlay is written

    // combine the 4 waves' fp64 partials in LDS (sequential, one-time)
    for (int w = 0; w < 4; ++w) {
        if (wq == w) {
#pragma unroll
            for (int t = 0; t < 4; ++t)
#pragma unroll
                for (int j = 0; j < 4; ++j) {
                    if (w == 0) L[4 * tg + t][4 * eg + j] = acc64[t][j];
                    else        L[4 * tg + t][4 * eg + j] += acc64[t][j];
                }
        }
        __syncthreads();
    }

    float* dispatch = out;
    float* probs    = out + (size_t)TTOT * NEXP;
    float* tkp      = out + (size_t)2 * TTOT * NEXP;
    float* tki      = tkp + (size_t)TTOT * 2;

    // each wave: softmax + top-2 for 4 tokens, lane = expert (proven code)
#pragma unroll
    for (int tt = 0; tt < 4; ++tt) {
        const int te = wq * 4 + tt;
        const int gt = tokBase + te;
        const float Lg = (float)L[te][lane];

        float m = Lg;
#pragma unroll
        for (int off = 32; off; off >>= 1) m = fmaxf(m, __shfl_xor(m, off, 64));
        const float p = expf(Lg - m);
        float sden = p;
#pragma unroll
        for (int off = 32; off; off >>= 1) sden += __shfl_xor(sden, off, 64);
        const float prob = p / sden;

        // top-1 (ties -> lowest index, matching lax.top_k / np)
        float v1 = prob; int i1 = lane;
#pragma unroll
        for (int off = 32; off; off >>= 1) {
            const float ov = __shfl_xor(v1, off, 64);
            const int   oi = __shfl_xor(i1, off, 64);
            if (ov > v1 || (ov == v1 && oi < i1)) { v1 = ov; i1 = oi; }
        }
        // top-2
        float v2 = (lane == i1) ? -1.0f : prob; int i2 = lane;
#pragma unroll
        for (int off = 32; off; off >>= 1) {
            const float ov = __shfl_xor(v2, off, 64);
            const int   oi = __shfl_xor(i2, off, 64);
            if (ov > v2 || (ov == v2 && oi < i2)) { v2 = ov; i2 = oi; }
        }

        probs[(size_t)gt * NEXP + lane]    = prob;
        dispatch[(size_t)gt * NEXP + lane] = (lane == i1 || lane == i2) ? 1.0f : 0.0f;
        if (lane == 0) {
            tkp[(size_t)gt * 2 + 0] = v1;
            tkp[(size_t)gt * 2 + 1] = v2;
            tki[(size_t)gt * 2 + 0] = (float)i1;
            tki[(size_t)gt * 2 + 1] = (float)i2;
        }
    }
}

extern "C" void kernel_launch(void* const* d_in, const int* in_sizes, int n_in,
                              void* d_out, int out_size, void* d_ws, size_t ws_size,
                              hipStream_t stream) {
    const float* x = (const float*)d_in[0];
    const float* W = (const float*)d_in[1];
    float* out = (float*)d_out;
    moe_router<<<TTOT / TPB, 256, 0, stream>>>(x, W, out);
}

// Round 3
// 239.754 us; speedup vs baseline: 7.6209x; 7.6209x over previous
//
#include <hip/hip_runtime.h>

#define TTOT 16384        // 4 * 4096 tokens
#define DDIM 2048
#define NEXP 64
#define TPB  32           // tokens per block (GEMM kernel)
#define KCH  256          // K-chunk per wave (DDIM / 8 waves)
#define W3TERM (NEXP * DDIM)   // 131072 elems per split term

typedef __attribute__((ext_vector_type(8))) short bf16x8;
typedef __attribute__((ext_vector_type(4))) float f32x4;
typedef __attribute__((ext_vector_type(4))) unsigned int u32x4;

// ---------------------------------------------------------------------------
// Exact fp32 -> 3x bf16 truncation split. For normal x: xh keeps top 8
// mantissa bits, r1 = x - xh is exact (<=16 sig bits), xm top 8 of r1,
// r2 = r1 - xm exact (<=8 sig bits) => r2 IS a bf16 value (low 16 bits of
// its fp32 encoding are zero). x == xh + xm + xl bit-exactly.
// ---------------------------------------------------------------------------
__device__ __forceinline__ void split3(const f32x4 va, const f32x4 vb,
                                       bf16x8& h, bf16x8& m, bf16x8& l)
{
    const float f[8] = {va.x, va.y, va.z, va.w, vb.x, vb.y, vb.z, vb.w};
    unsigned int hu[8], mu[8], lu[8];
#pragma unroll
    for (int j = 0; j < 8; ++j) {
        const unsigned int xb = __float_as_uint(f[j]);
        const unsigned int hb = xb & 0xffff0000u;
        const float r1 = f[j] - __uint_as_float(hb);
        const unsigned int mb = __float_as_uint(r1) & 0xffff0000u;
        const float r2 = r1 - __uint_as_float(mb);
        hu[j] = hb; mu[j] = mb; lu[j] = __float_as_uint(r2);
    }
    u32x4 hw, mw, lw;
#pragma unroll
    for (int w = 0; w < 4; ++w) {
        hw[w] = (hu[2 * w] >> 16) | (mu[2 * w] & 0u) | (hu[2 * w + 1] & 0xffff0000u);
        mw[w] = (mu[2 * w] >> 16) | (mu[2 * w + 1] & 0xffff0000u);
        lw[w] = (lu[2 * w] >> 16) | (lu[2 * w + 1] & 0xffff0000u);
    }
    h = __builtin_bit_cast(bf16x8, hw);
    m = __builtin_bit_cast(bf16x8, mw);
    l = __builtin_bit_cast(bf16x8, lw);
}

// ---------------------------------------------------------------------------
// Prep: split W [2048][64] fp32 into W3[3][64][2048] bf16 (transposed so the
// MFMA B-fragment = 8 contiguous d = one dwordx4). Coalesced 2B writes.
// ---------------------------------------------------------------------------
__global__ __launch_bounds__(256)
void w_split(const float* __restrict__ W, unsigned short* __restrict__ W3)
{
    const int q = blockIdx.x * 256 + threadIdx.x;   // 0 .. 131071
    const int e = q >> 11;                          // 0..63
    const int d = q & 2047;                         // 0..2047
    const float w = W[(size_t)d * NEXP + e];
    const unsigned int xb = __float_as_uint(w);
    const unsigned int hb = xb & 0xffff0000u;
    const float r1 = w - __uint_as_float(hb);
    const unsigned int mb = __float_as_uint(r1) & 0xffff0000u;
    const float r2 = r1 - __uint_as_float(mb);
    const unsigned int lb = __float_as_uint(r2);
    const size_t o = (size_t)e * DDIM + d;
    W3[o]              = (unsigned short)(hb >> 16);
    W3[o + W3TERM]     = (unsigned short)(mb >> 16);
    W3[o + 2 * W3TERM] = (unsigned short)(lb >> 16);
}

// ---------------------------------------------------------------------------
// GEMM: 512 blocks x 512 thr. Wave wq owns K-chunk [wq*256, wq*256+256) for
// the block's 32 tokens x 64 experts. Per K-step (32 d): A = 2 M-tiles read
// from global fp32 (rolled prefetch) + exact split3; B = 4 N-tiles x 3 terms
// from W3 (L2-resident); 48 MFMA (6 cross-product passes). fp32 LDS combine
// across the 8 waves, then the R1-proven softmax/top-2 epilogue.
// mfma_f32_16x16x32_bf16 layouts (m89-verified family): A row = lane&15,
// k = (lane>>4)*8+j ; B col = lane&15, same k ; D col = lane&15,
// row = (lane>>4)*4+reg.
// ---------------------------------------------------------------------------
__global__ __launch_bounds__(512, 2)
void moe_gemm(const float* __restrict__ x, const unsigned short* __restrict__ W3,
              float* __restrict__ out)
{
    __shared__ float L[TPB][NEXP + 1];   // 32 x 65 fp32 = 8.3 KB
    const int tid  = threadIdx.x;
    const int lane = tid & 63;
    const int wq   = __builtin_amdgcn_readfirstlane(tid >> 6);  // 0..7
    const int lrow = lane & 15;          // A row / B col
    const int lk   = lane >> 4;          // k-group (0..3)
    const int tokBase = blockIdx.x * TPB;

    f32x4 c[2][4];
#pragma unroll
    for (int mt = 0; mt < 2; ++mt)
#pragma unroll
        for (int nt = 0; nt < 4; ++nt)
            c[mt][nt] = (f32x4){0.0f, 0.0f, 0.0f, 0.0f};

    const int kBase = wq * KCH;
    const float* xp0 = x + (size_t)(tokBase + lrow) * DDIM + kBase + lk * 8;
    const float* xp1 = xp0 + (size_t)16 * DDIM;
    const unsigned short* wp = W3 + (size_t)lrow * DDIM + kBase + lk * 8;

    // prologue: first A raw loads
    f32x4 r0a = *(const f32x4*)(xp0);
    f32x4 r0b = *(const f32x4*)(xp0 + 4);
    f32x4 r1a = *(const f32x4*)(xp1);
    f32x4 r1b = *(const f32x4*)(xp1 + 4);

    for (int ks = 0; ks < KCH / 32; ++ks) {   // 8 iters
        const f32x4 c0a = r0a, c0b = r0b, c1a = r1a, c1b = r1b;
        if (ks < KCH / 32 - 1) {              // prefetch next A (HBM latency)
            const float* nx0 = xp0 + (ks + 1) * 32;
            const float* nx1 = xp1 + (ks + 1) * 32;
            r0a = *(const f32x4*)(nx0);
            r0b = *(const f32x4*)(nx0 + 4);
            r1a = *(const f32x4*)(nx1);
            r1b = *(const f32x4*)(nx1 + 4);
        }

        // B loads: 4 N-tiles x {hi, mid, lo} (L2-resident, issued before the
        // conversion VALU burst so latency hides under it)
        bf16x8 bh[4], bm[4], bl[4];
#pragma unroll
        for (int nt = 0; nt < 4; ++nt) {
            const unsigned short* bp = wp + (size_t)nt * 16 * DDIM + ks * 32;
            bh[nt] = *(const bf16x8*)(bp);
            bm[nt] = *(const bf16x8*)(bp + W3TERM);
            bl[nt] = *(const bf16x8*)(bp + 2 * W3TERM);
        }

        // A conversion (exact 3-way split)
        bf16x8 ah0, am0, al0, ah1, am1, al1;
        split3(c0a, c0b, ah0, am0, al0);
        split3(c1a, c1b, ah1, am1, al1);

        // 6 passes x 2 M x 4 N = 48 MFMA, pass-major for 8-way acc ILP
#pragma unroll
        for (int nt = 0; nt < 4; ++nt) c[0][nt] = __builtin_amdgcn_mfma_f32_16x16x32_bf16(ah0, bh[nt], c[0][nt], 0, 0, 0);
#pragma unroll
        for (int nt = 0; nt < 4; ++nt) c[1][nt] = __builtin_amdgcn_mfma_f32_16x16x32_bf16(ah1, bh[nt], c[1][nt], 0, 0, 0);
#pragma unroll
        for (int nt = 0; nt < 4; ++nt) c[0][nt] = __builtin_amdgcn_mfma_f32_16x16x32_bf16(ah0, bm[nt], c[0][nt], 0, 0, 0);
#pragma unroll
        for (int nt = 0; nt < 4; ++nt) c[1][nt] = __builtin_amdgcn_mfma_f32_16x16x32_bf16(ah1, bm[nt], c[1][nt], 0, 0, 0);
#pragma unroll
        for (int nt = 0; nt < 4; ++nt) c[0][nt] = __builtin_amdgcn_mfma_f32_16x16x32_bf16(am0, bh[nt], c[0][nt], 0, 0, 0);
#pragma unroll
        for (int nt = 0; nt < 4; ++nt) c[1][nt] = __builtin_amdgcn_mfma_f32_16x16x32_bf16(am1, bh[nt], c[1][nt], 0, 0, 0);
#pragma unroll
        for (int nt = 0; nt < 4; ++nt) c[0][nt] = __builtin_amdgcn_mfma_f32_16x16x32_bf16(ah0, bl[nt], c[0][nt], 0, 0, 0);
#pragma unroll
        for (int nt = 0; nt < 4; ++nt) c[1][nt] = __builtin_amdgcn_mfma_f32_16x16x32_bf16(ah1, bl[nt], c[1][nt], 0, 0, 0);
#pragma unroll
        for (int nt = 0; nt < 4; ++nt) c[0][nt] = __builtin_amdgcn_mfma_f32_16x16x32_bf16(al0, bh[nt], c[0][nt], 0, 0, 0);
#pragma unroll
        for (int nt = 0; nt < 4; ++nt) c[1][nt] = __builtin_amdgcn_mfma_f32_16x16x32_bf16(al1, bh[nt], c[1][nt], 0, 0, 0);
#pragma unroll
        for (int nt = 0; nt < 4; ++nt) c[0][nt] = __builtin_amdgcn_mfma_f32_16x16x32_bf16(am0, bm[nt], c[0][nt], 0, 0, 0);
#pragma unroll
        for (int nt = 0; nt < 4; ++nt) c[1][nt] = __builtin_amdgcn_mfma_f32_16x16x32_bf16(am1, bm[nt], c[1][nt], 0, 0, 0);
    }

    // combine the 8 waves' fp32 K-chunk partials in LDS (one-time)
    for (int w = 0; w < 8; ++w) {
        if (wq == w) {
#pragma unroll
            for (int mt = 0; mt < 2; ++mt)
#pragma unroll
                for (int nt = 0; nt < 4; ++nt)
#pragma unroll
                    for (int i = 0; i < 4; ++i) {
                        const int row = mt * 16 + lk * 4 + i;  // token in block
                        const int col = nt * 16 + lrow;        // expert
                        if (w == 0) L[row][col]  = c[mt][nt][i];
                        else        L[row][col] += c[mt][nt][i];
                    }
        }
        __syncthreads();
    }

    float* dispatch = out;
    float* probs    = out + (size_t)TTOT * NEXP;
    float* tkp      = out + (size_t)2 * TTOT * NEXP;
    float* tki      = tkp + (size_t)TTOT * 2;

    // each wave: softmax + top-2 for 4 tokens, lane = expert (R1-proven code)
#pragma unroll
    for (int tt = 0; tt < 4; ++tt) {
        const int te = wq * 4 + tt;
        const int gt = tokBase + te;
        const float Lg = L[te][lane];

        float m = Lg;
#pragma unroll
        for (int off = 32; off; off >>= 1) m = fmaxf(m, __shfl_xor(m, off, 64));
        const float p = expf(Lg - m);
        float sden = p;
#pragma unroll
        for (int off = 32; off; off >>= 1) sden += __shfl_xor(sden, off, 64);
        const float prob = p / sden;

        // top-1 (ties -> lowest index, matching lax.top_k / np)
        float v1 = prob; int i1 = lane;
#pragma unroll
        for (int off = 32; off; off >>= 1) {
            const float ov = __shfl_xor(v1, off, 64);
            const int   oi = __shfl_xor(i1, off, 64);
            if (ov > v1 || (ov == v1 && oi < i1)) { v1 = ov; i1 = oi; }
        }
        // top-2
        float v2 = (lane == i1) ? -1.0f : prob; int i2 = lane;
#pragma unroll
        for (int off = 32; off; off >>= 1) {
            const float ov = __shfl_xor(v2, off, 64);
            const int   oi = __shfl_xor(i2, off, 64);
            if (ov > v2 || (ov == v2 && oi < i2)) { v2 = ov; i2 = oi; }
        }

        probs[(size_t)gt * NEXP + lane]    = prob;
        dispatch[(size_t)gt * NEXP + lane] = (lane == i1 || lane == i2) ? 1.0f : 0.0f;
        if (lane == 0) {
            tkp[(size_t)gt * 2 + 0] = v1;
            tkp[(size_t)gt * 2 + 1] = v2;
            tki[(size_t)gt * 2 + 0] = (float)i1;
            tki[(size_t)gt * 2 + 1] = (float)i2;
        }
    }
}

extern "C" void kernel_launch(void* const* d_in, const int* in_sizes, int n_in,
                              void* d_out, int out_size, void* d_ws, size_t ws_size,
                              hipStream_t stream) {
    const float* x = (const float*)d_in[0];
    const float* W = (const float*)d_in[1];
    float* out = (float*)d_out;
    unsigned short* W3 = (unsigned short*)d_ws;   // 3 * 64 * 2048 * 2B = 768 KB

    w_split<<<512, 256, 0, stream>>>(W, W3);
    moe_gemm<<<TTOT / TPB, 512, 0, stream>>>(x, W3, out);
}

// Round 4
// 215.123 us; speedup vs baseline: 8.4935x; 1.1145x over previous
//
#include <hip/hip_runtime.h>

#define TTOT 16384        // 4 * 4096 tokens
#define DDIM 2048
#define NEXP 64
#define TPB  32           // tokens per block (GEMM kernel)
#define KCH  256          // K-chunk per wave (DDIM / 8 waves)
#define NKS  8            // k-steps per wave (KCH / 32)
#define WTERM (NEXP * DDIM)   // 131072 elems per split term

typedef __attribute__((ext_vector_type(8))) short bf16x8;
typedef __attribute__((ext_vector_type(4))) float f32x4;
typedef __attribute__((ext_vector_type(4))) unsigned int u32x4;

// ---------------------------------------------------------------------------
// Exact fp32 -> 3x bf16 truncation split (proven R3). x == xh + xm + xl.
// ---------------------------------------------------------------------------
__device__ __forceinline__ void split3(const f32x4 va, const f32x4 vb,
                                       bf16x8& h, bf16x8& m, bf16x8& l)
{
    const float f[8] = {va.x, va.y, va.z, va.w, vb.x, vb.y, vb.z, vb.w};
    unsigned int hu[8], mu[8], lu[8];
#pragma unroll
    for (int j = 0; j < 8; ++j) {
        const unsigned int xb = __float_as_uint(f[j]);
        const unsigned int hb = xb & 0xffff0000u;
        const float r1 = f[j] - __uint_as_float(hb);
        const unsigned int mb = __float_as_uint(r1) & 0xffff0000u;
        const float r2 = r1 - __uint_as_float(mb);
        hu[j] = hb; mu[j] = mb; lu[j] = __float_as_uint(r2);
    }
    u32x4 hw, mw, lw;
#pragma unroll
    for (int w = 0; w < 4; ++w) {
        hw[w] = (hu[2 * w] >> 16) | (hu[2 * w + 1] & 0xffff0000u);
        mw[w] = (mu[2 * w] >> 16) | (mu[2 * w + 1] & 0xffff0000u);
        lw[w] = (lu[2 * w] >> 16) | (lu[2 * w + 1] & 0xffff0000u);
    }
    h = __builtin_bit_cast(bf16x8, hw);
    m = __builtin_bit_cast(bf16x8, mw);
    l = __builtin_bit_cast(bf16x8, lw);
}

// ---------------------------------------------------------------------------
// Prep: split W [2048][64] fp32 into W4[3][256 kg][64 e][8 d] bf16.
// B-fragment (expert e, d = kg*8..kg*8+7) = one 16B load; a wave's 64-lane
// B load now covers 4 contiguous 256B segments (was 16x64B scattered).
// ---------------------------------------------------------------------------
__global__ __launch_bounds__(256)
void w_split(const float* __restrict__ W, unsigned short* __restrict__ W4)
{
    const int q = blockIdx.x * 256 + threadIdx.x;   // 0 .. 131071
    const int e = q >> 11;                          // 0..63
    const int d = q & 2047;                         // 0..2047
    const float w = W[(size_t)d * NEXP + e];
    const unsigned int xb = __float_as_uint(w);
    const unsigned int hb = xb & 0xffff0000u;
    const float r1 = w - __uint_as_float(hb);
    const unsigned int mb = __float_as_uint(r1) & 0xffff0000u;
    const float r2 = r1 - __uint_as_float(mb);
    const unsigned int lb = __float_as_uint(r2);
    const size_t o = ((size_t)(d >> 3) * 64 + e) * 8 + (d & 7);
    W4[o]             = (unsigned short)(hb >> 16);
    W4[o + WTERM]     = (unsigned short)(mb >> 16);
    W4[o + 2 * WTERM] = (unsigned short)(lb >> 16);
}

// ---------------------------------------------------------------------------
// GEMM: 512 blocks x 512 thr (8 waves). Wave wq owns K-chunk
// [wq*256, wq*256+256) for the block's 32 tokens x 64 experts. x is staged
// per-wave per-k-step into a PRIVATE 4KB LDS sub-tile via global_load_lds
// (async, double-buffered, NO barriers in the K-loop: waves fully decoupled,
// one vmcnt(0) per iter covered by a full iteration of compute). LDS layout
// granule-XOR-swizzled (g ^= row&7) with the inverse swizzle applied to the
// per-lane GLOBAL source address (linear LDS dest, rule: both-sides-or-
// neither), so the A ds_read_b128 is bank-balanced (8 lanes / 4-bank group
// = b128 minimum). B from W4 in L2 (12 coalesced 16B/lane loads per k-step).
// Arithmetic sequence bit-identical to R3 (same elements, same MFMA order).
// ---------------------------------------------------------------------------
__global__ __launch_bounds__(512, 4)
void moe_gemm(const float* __restrict__ x, const unsigned short* __restrict__ W4,
              float* __restrict__ out)
{
    __shared__ float xs[2][8][32][32];   // 64 KB: [buf][wave][token][d]
    __shared__ float L[TPB][NEXP + 1];   // 8.3 KB combine buffer
    const int tid  = threadIdx.x;
    const int lane = tid & 63;
    const int wq   = __builtin_amdgcn_readfirstlane(tid >> 6);  // 0..7
    const int lrow = lane & 15;          // A row (token) / B col (expert)
    const int lk   = lane >> 4;          // k-group (0..3)
    const int tokBase = blockIdx.x * TPB;
    const int kBase   = wq * KCH;

    f32x4 c[2][4];
#pragma unroll
    for (int mt = 0; mt < 2; ++mt)
#pragma unroll
        for (int nt = 0; nt < 4; ++nt)
            c[mt][nt] = (f32x4){0.0f, 0.0f, 0.0f, 0.0f};

    // --- stage-side mapping -------------------------------------------------
    // physical granule p = call*64 + lane -> row = call*8 + (lane>>3),
    // col q = lane&7. Content must be logical granule q ^ (row&7)
    // = (lane&7) ^ (lane>>3)  (call-invariant). 16B granules, rows = tokens.
    const int srow = lane >> 3;                     // 0..7
    const int scol = (lane & 7) ^ srow;             // pre-swizzled source col
    const float* sBase = x + (size_t)(tokBase + srow) * DDIM + kBase + scol * 4;

#define STAGE(ksn, dstbuf)                                                     \
    {                                                                          \
        const float* g_ = sBase + (ksn) * 32;                                  \
        float* l_ = &xs[dstbuf][wq][0][0];                                     \
        _Pragma("unroll")                                                      \
        for (int cc = 0; cc < 4; ++cc)                                         \
            __builtin_amdgcn_global_load_lds(                                  \
                (const __attribute__((address_space(1))) unsigned int*)        \
                    (g_ + cc * 8 * DDIM),                                      \
                (__attribute__((address_space(3))) unsigned int*)              \
                    (l_ + cc * 256),                                           \
                16, 0, 0);                                                     \
    }

    // --- read-side mapping: logical granule g=lk*2 -> physical g^(lrow&7) ---
    const int ph    = (lk * 2) ^ (lrow & 7);        // physical granule col
    const int aoff0 = lrow * 32 + ph * 4;           // mt=0 float offset
    const int aoff1 = (16 + lrow) * 32 + ph * 4;    // mt=1 (same row&7 -> same ph)

    // --- B pointers (L2-resident W4) ----------------------------------------
    const unsigned short* bph = W4 + (size_t)(((kBase >> 3) + lk) * 512 + lrow * 8);
    const unsigned short* bpm = bph + WTERM;
    const unsigned short* bpl = bpm + WTERM;

    // prologue: stage k-step 0 into buf 0
    STAGE(0, 0)

#pragma unroll 2
    for (int ks = 0; ks < NKS; ++ks) {
        // stage(ks) complete (issued one full iteration ago)
        asm volatile("s_waitcnt vmcnt(0)" ::: "memory");
        const int buf = ks & 1;
        if (ks + 1 < NKS) STAGE(ks + 1, buf ^ 1)

        // B loads (coalesced; compiler schedules against MFMA uses)
        bf16x8 bh[4], bm[4], bl[4];
#pragma unroll
        for (int nt = 0; nt < 4; ++nt) {
            bh[nt] = *(const bf16x8*)(bph + nt * 128);
            bm[nt] = *(const bf16x8*)(bpm + nt * 128);
            bl[nt] = *(const bf16x8*)(bpl + nt * 128);
        }
        bph += 2048; bpm += 2048; bpl += 2048;

        // A from LDS (swizzled read), then exact 3-way split
        const float* sub = &xs[buf][wq][0][0];
        const f32x4 c0a = *(const f32x4*)(sub + aoff0);
        const f32x4 c0b = *(const f32x4*)(sub + (aoff0 ^ 4));
        const f32x4 c1a = *(const f32x4*)(sub + aoff1);
        const f32x4 c1b = *(const f32x4*)(sub + (aoff1 ^ 4));
        bf16x8 ah0, am0, al0, ah1, am1, al1;
        split3(c0a, c0b, ah0, am0, al0);
        split3(c1a, c1b, ah1, am1, al1);

        // 6 passes x 2 M x 4 N = 48 MFMA (verbatim R3 order -> bit-identical)
#pragma unroll
        for (int nt = 0; nt < 4; ++nt) c[0][nt] = __builtin_amdgcn_mfma_f32_16x16x32_bf16(ah0, bh[nt], c[0][nt], 0, 0, 0);
#pragma unroll
        for (int nt = 0; nt < 4; ++nt) c[1][nt] = __builtin_amdgcn_mfma_f32_16x16x32_bf16(ah1, bh[nt], c[1][nt], 0, 0, 0);
#pragma unroll
        for (int nt = 0; nt < 4; ++nt) c[0][nt] = __builtin_amdgcn_mfma_f32_16x16x32_bf16(ah0, bm[nt], c[0][nt], 0, 0, 0);
#pragma unroll
        for (int nt = 0; nt < 4; ++nt) c[1][nt] = __builtin_amdgcn_mfma_f32_16x16x32_bf16(ah1, bm[nt], c[1][nt], 0, 0, 0);
#pragma unroll
        for (int nt = 0; nt < 4; ++nt) c[0][nt] = __builtin_amdgcn_mfma_f32_16x16x32_bf16(am0, bh[nt], c[0][nt], 0, 0, 0);
#pragma unroll
        for (int nt = 0; nt < 4; ++nt) c[1][nt] = __builtin_amdgcn_mfma_f32_16x16x32_bf16(am1, bh[nt], c[1][nt], 0, 0, 0);
#pragma unroll
        for (int nt = 0; nt < 4; ++nt) c[0][nt] = __builtin_amdgcn_mfma_f32_16x16x32_bf16(ah0, bl[nt], c[0][nt], 0, 0, 0);
#pragma unroll
        for (int nt = 0; nt < 4; ++nt) c[1][nt] = __builtin_amdgcn_mfma_f32_16x16x32_bf16(ah1, bl[nt], c[1][nt], 0, 0, 0);
#pragma unroll
        for (int nt = 0; nt < 4; ++nt) c[0][nt] = __builtin_amdgcn_mfma_f32_16x16x32_bf16(al0, bh[nt], c[0][nt], 0, 0, 0);
#pragma unroll
        for (int nt = 0; nt < 4; ++nt) c[1][nt] = __builtin_amdgcn_mfma_f32_16x16x32_bf16(al1, bh[nt], c[1][nt], 0, 0, 0);
#pragma unroll
        for (int nt = 0; nt < 4; ++nt) c[0][nt] = __builtin_amdgcn_mfma_f32_16x16x32_bf16(am0, bm[nt], c[0][nt], 0, 0, 0);
#pragma unroll
        for (int nt = 0; nt < 4; ++nt) c[1][nt] = __builtin_amdgcn_mfma_f32_16x16x32_bf16(am1, bm[nt], c[1][nt], 0, 0, 0);
    }
#undef STAGE

    // combine the 8 waves' fp32 K-chunk partials in LDS (one-time, proven)
    for (int w = 0; w < 8; ++w) {
        if (wq == w) {
#pragma unroll
            for (int mt = 0; mt < 2; ++mt)
#pragma unroll
                for (int nt = 0; nt < 4; ++nt)
#pragma unroll
                    for (int i = 0; i < 4; ++i) {
                        const int row = mt * 16 + lk * 4 + i;  // token in block
                        const int col = nt * 16 + lrow;        // expert
                        if (w == 0) L[row][col]  = c[mt][nt][i];
                        else        L[row][col] += c[mt][nt][i];
                    }
        }
        __syncthreads();
    }

    float* dispatch = out;
    float* probs    = out + (size_t)TTOT * NEXP;
    float* tkp      = out + (size_t)2 * TTOT * NEXP;
    float* tki      = tkp + (size_t)TTOT * 2;

    // each wave: softmax + top-2 for 4 tokens, lane = expert (proven code)
#pragma unroll
    for (int tt = 0; tt < 4; ++tt) {
        const int te = wq * 4 + tt;
        const int gt = tokBase + te;
        const float Lg = L[te][lane];

        float m = Lg;
#pragma unroll
        for (int off = 32; off; off >>= 1) m = fmaxf(m, __shfl_xor(m, off, 64));
        const float p = expf(Lg - m);
        float sden = p;
#pragma unroll
        for (int off = 32; off; off >>= 1) sden += __shfl_xor(sden, off, 64);
        const float prob = p / sden;

        // top-1 (ties -> lowest index, matching lax.top_k / np)
        float v1 = prob; int i1 = lane;
#pragma unroll
        for (int off = 32; off; off >>= 1) {
            const float ov = __shfl_xor(v1, off, 64);
            const int   oi = __shfl_xor(i1, off, 64);
            if (ov > v1 || (ov == v1 && oi < i1)) { v1 = ov; i1 = oi; }
        }
        // top-2
        float v2 = (lane == i1) ? -1.0f : prob; int i2 = lane;
#pragma unroll
        for (int off = 32; off; off >>= 1) {
            const float ov = __shfl_xor(v2, off, 64);
            const int   oi = __shfl_xor(i2, off, 64);
            if (ov > v2 || (ov == v2 && oi < i2)) { v2 = ov; i2 = oi; }
        }

        probs[(size_t)gt * NEXP + lane]    = prob;
        dispatch[(size_t)gt * NEXP + lane] = (lane == i1 || lane == i2) ? 1.0f : 0.0f;
        if (lane == 0) {
            tkp[(size_t)gt * 2 + 0] = v1;
            tkp[(size_t)gt * 2 + 1] = v2;
            tki[(size_t)gt * 2 + 0] = (float)i1;
            tki[(size_t)gt * 2 + 1] = (float)i2;
        }
    }
}

extern "C" void kernel_launch(void* const* d_in, const int* in_sizes, int n_in,
                              void* d_out, int out_size, void* d_ws, size_t ws_size,
                              hipStream_t stream) {
    const float* x = (const float*)d_in[0];
    const float* W = (const float*)d_in[1];
    float* out = (float*)d_out;
    unsigned short* W4 = (unsigned short*)d_ws;   // 3 * 131072 * 2B = 768 KB

    w_split<<<512, 256, 0, stream>>>(W, W4);
    moe_gemm<<<TTOT / TPB, 512, 0, stream>>>(x, W4, out);
}